// Round 9
// baseline (539.749 us; speedup 1.0000x reference)
//
#include <hip/hip_runtime.h>

// ---------------------------------------------------------------------------
// MoNet GNN: N=50000, E=800000, H=128, K=3, L=4, pdim=2, G=50, npg=1000
// Round 9: agg latency fix — fully-masked 16-edge blocks (no serial 2-edge
//          remainder; 8 gathers/lane always in flight; cndmask-zeroed tail)
//          + revert edge streams to psrc(int) + float4 f32 gw (no fp16 cvts).
//          Keeps R8 XCD-graph affinity swizzle, bf16 h, bucketed CSR,
//          BN fused in GEMM epilogue.
// ---------------------------------------------------------------------------

typedef unsigned char  u8;
typedef unsigned short u16;
typedef unsigned int   u32;
typedef __attribute__((ext_vector_type(8))) short bf16x8;
typedef __attribute__((ext_vector_type(4))) float f32x4;

__device__ __forceinline__ u16 f2b(float f) {
    union { float f; u32 u; } v; v.f = f;
    u32 u = v.u;
    u32 r = (u + 0x7fffu + ((u >> 16) & 1u)) >> 16;   // RNE
    return (u16)r;
}
__device__ __forceinline__ float blo(u32 h) {
    union { u32 u; float f; } v; v.u = h << 16; return v.f;
}
__device__ __forceinline__ float bhi(u32 h) {
    union { u32 u; float f; } v; v.u = h & 0xffff0000u; return v.f;
}

// ---- fp32 -> bf16 conversion (x4 per thread)
__global__ void cvt_bf16(const float* __restrict__ in, u16* __restrict__ out, int n4) {
    int i = blockIdx.x * 256 + threadIdx.x;
    if (i >= n4) return;
    float4 v = ((const float4*)in)[i];
    ushort4 o; o.x = f2b(v.x); o.y = f2b(v.y); o.z = f2b(v.z); o.w = f2b(v.w);
    ((ushort4*)out)[i] = o;
}

// ---- prep emb_W^T in bf16: Bt[n][k] = emb_W[k*128+n]
__global__ void prep_embW(const float* __restrict__ W, u16* __restrict__ Bt) {
    int idx = blockIdx.x * 256 + threadIdx.x;   // 16384
    int n = idx >> 7, k = idx & 127;
    Bt[idx] = f2b(W[k * 128 + n]);
}

// ---- prep fc weights: Bp[l][n][kc*128+r] = fcW[l][r][kc*128+n]  (bf16, B^T)
__global__ void prep_fcW(const float* __restrict__ W, u16* __restrict__ Bp, int total) {
    int idx = blockIdx.x * 256 + threadIdx.x;   // L*128*384
    if (idx >= total) return;
    int kk = idx % 384;
    int rest = idx / 384;
    int n = rest & 127;
    int l = rest >> 7;
    int kc = kk >> 7, r = kk & 127;
    Bp[idx] = f2b(W[((size_t)(l * 128 + r)) * 384 + kc * 128 + n]);
}

// ---- in-degree histogram
__global__ void hist_kernel(const int* __restrict__ dst, int* __restrict__ cnt, int E) {
    int e = blockIdx.x * 256 + threadIdx.x;
    if (e < E) atomicAdd(&cnt[dst[e]], 1);
}

// ---- 3-phase exclusive scan of cnt[N] -> rs[N+1]
__global__ void scan_partial(const int* __restrict__ cnt, int* __restrict__ bsum, int N) {
    __shared__ int buf[256];
    int t = threadIdx.x, base = blockIdx.x * 256;
    buf[t] = (base + t < N) ? cnt[base + t] : 0;
    __syncthreads();
    for (int off = 128; off > 0; off >>= 1) {
        if (t < off) buf[t] += buf[t + off];
        __syncthreads();
    }
    if (t == 0) bsum[blockIdx.x] = buf[0];
}
__global__ void scan_bsums(const int* __restrict__ bsum, int* __restrict__ boff, int nb) {
    __shared__ int buf[256];
    int t = threadIdx.x;
    int v = (t < nb) ? bsum[t] : 0;
    buf[t] = v;
    __syncthreads();
    for (int off = 1; off < 256; off <<= 1) {
        int x = (t >= off) ? buf[t - off] : 0;
        __syncthreads();
        buf[t] += x;
        __syncthreads();
    }
    if (t < nb) boff[t] = buf[t] - v;   // exclusive
}
__global__ void scan_final(const int* __restrict__ cnt, const int* __restrict__ boff,
                           int* __restrict__ rs, int N) {
    __shared__ int buf[256];
    int t = threadIdx.x, base = blockIdx.x * 256;
    int v = (base + t < N) ? cnt[base + t] : 0;
    buf[t] = v;
    __syncthreads();
    for (int off = 1; off < 256; off <<= 1) {
        int x = (t >= off) ? buf[t - off] : 0;
        __syncthreads();
        buf[t] += x;
        __syncthreads();
    }
    if (base + t < N) rs[base + t + 1] = boff[blockIdx.x] + buf[t];
    if (base == 0 && t == 0) rs[0] = 0;
}

// ---- Pass A: bin 4096 edges per block by graph (LDS), chunk-copy to tmp
__global__ __launch_bounds__(256) void bucketA(const int* __restrict__ src,
                                               const int* __restrict__ dst,
                                               const int* __restrict__ rs,
                                               int* __restrict__ gcur,
                                               u32* __restrict__ tmp,
                                               int E, int npg, int G) {
    __shared__ u32 ebuf[4096];
    __shared__ u8  gmap[4096];
    __shared__ int ghist[64], gexc[64], gbase[64], lcur[64];
    const int tid = threadIdx.x;
    const int e0 = blockIdx.x * 4096;
    const int n = min(4096, E - e0);
    if (tid < 64) { ghist[tid] = 0; lcur[tid] = 0; }
    __syncthreads();
    for (int i = tid; i < n; i += 256) {
        int g = dst[e0 + i] / npg;
        atomicAdd(&ghist[g], 1);
    }
    __syncthreads();
    if (tid == 0) {
        int acc = 0;
        for (int g = 0; g < G; g++) { gexc[g] = acc; acc += ghist[g]; }
    }
    __syncthreads();
    if (tid < G) {
        int c = ghist[tid];
        gbase[tid] = (c > 0) ? rs[tid * npg] + atomicAdd(&gcur[tid], c) : 0;
    }
    __syncthreads();
    for (int i = tid; i < n; i += 256) {
        int d = dst[e0 + i];
        int g = d / npg;
        int pos = gexc[g] + atomicAdd(&lcur[g], 1);
        ebuf[pos] = ((u32)src[e0 + i] << 16) | (u32)(d - g * npg);
        gmap[pos] = (u8)g;
    }
    __syncthreads();
    for (int i = tid; i < n; i += 256) {
        int g = gmap[i];
        tmp[gbase[g] + (i - gexc[g])] = ebuf[i];
    }
}

// ---- Pass B: one block per graph, counting-scatter to psrc via LDS cursors
__global__ __launch_bounds__(1024) void bucketB(const u32* __restrict__ tmp,
                                                const int* __restrict__ rs,
                                                int* __restrict__ psrc,
                                                int npg) {
    __shared__ int rsl[1025];
    __shared__ int lcur[1024];
    const int g = blockIdx.x, tid = threadIdx.x;
    const int base = g * npg;
    for (int i = tid; i <= npg; i += 1024) rsl[i] = rs[base + i];
    for (int i = tid; i < npg; i += 1024) lcur[i] = 0;
    __syncthreads();
    const int p0 = rsl[0], p1 = rsl[npg];
    for (int p = p0 + tid; p < p1; p += 1024) {
        u32 v = tmp[p];
        int dl = v & 0xffffu;
        int pos = rsl[dl] + atomicAdd(&lcur[dl], 1);
        psrc[pos] = (int)(v >> 16);
    }
}

// ---- fill pdst from CSR ranges (coalesced sequential writes)
__global__ void fill_pdst(const int* __restrict__ rs, int* __restrict__ pdst, int N) {
    int nid = blockIdx.x * 4 + (threadIdx.x >> 6);
    if (nid >= N) return;
    int lane = threadIdx.x & 63;
    int p0 = rs[nid], p1 = rs[nid + 1];
    for (int p = p0 + lane; p < p1; p += 64) pdst[p] = nid;
}

// ---- Gaussian weights in permuted order, all L layers, padded float4
//      layer stride Epad (E+16) for safe masked over-read in agg
__global__ void gw_kernel(const int* __restrict__ psrc, const int* __restrict__ pdst,
                          const int* __restrict__ cnt,
                          const float* __restrict__ ppW, const float* __restrict__ ppb,
                          const float* __restrict__ mu, const float* __restrict__ isig,
                          float* __restrict__ pgw, int E, int Epad, int L) {
    int p = blockIdx.x * 256 + threadIdx.x;
    if (p >= E) return;
    float ps0 = rsqrtf((float)cnt[psrc[p]] + 1.0f);
    float ps1 = rsqrtf((float)cnt[pdst[p]] + 1.0f);
    for (int l = 0; l < L; l++) {
        float p0 = tanhf(ps0 * ppW[l * 4 + 0] + ps1 * ppW[l * 4 + 2] + ppb[l * 2 + 0]);
        float p1 = tanhf(ps0 * ppW[l * 4 + 1] + ps1 * ppW[l * 4 + 3] + ppb[l * 2 + 1]);
        float4 o;
        float* ov = (float*)&o;
#pragma unroll
        for (int k = 0; k < 3; k++) {
            float d0 = (p0 - mu[(l * 3 + k) * 2 + 0]) * isig[(l * 3 + k) * 2 + 0];
            float d1 = (p1 - mu[(l * 3 + k) * 2 + 1]) * isig[(l * 3 + k) * 2 + 1];
            ov[k] = expf(-0.5f * (d0 * d0 + d1 * d1));
        }
        o.w = 0.f;
        ((float4*)pgw)[(size_t)l * Epad + p] = o;
    }
}

// ---- per-node aggregation, XCD-graph affinity, fully-masked 16-edge blocks.
//      One wave per node; lanes 0-31 even edge of pair, 32-63 odd; 4 bf16
//      channels per lane via uint2 gather. Every node: floor(d/16) unmasked
//      blocks + one masked block -> 8 gathers/lane always in flight (no
//      serial remainder chain). Tail edges: g cndmask'd to 0 (psrc padded).
__global__ __launch_bounds__(256) void agg_kernel(const u16* __restrict__ hb,
                                                  const float* __restrict__ pgw,   // layer base
                                                  const int* __restrict__ psrc,
                                                  const int* __restrict__ rs,
                                                  u16* __restrict__ t,
                                                  float* __restrict__ sk,
                                                  int npg, int bpg, int G) {
    const int wgid = blockIdx.x;
    const int xcd = wgid & 7;
    const int slot = wgid >> 3;
    const int g = xcd + ((slot / bpg) << 3);
    if (g >= G) return;
    const int nid = g * npg + (slot % bpg) * 4 + (threadIdx.x >> 6);

    int lane = threadIdx.x & 63;
    int half = lane >> 5;
    int cl = lane & 31;
    int p0 = __builtin_amdgcn_readfirstlane(rs[nid]);
    int p1 = __builtin_amdgcn_readfirstlane(rs[nid + 1]);
    float a0[4] = {}, a1[4] = {}, a2[4] = {};
    float gs0 = 0.f, gs1 = 0.f, gs2 = 0.f;
    const float4* pg4 = (const float4*)pgw;
    int p = p0;
    // unmasked full blocks
    for (; p + 16 <= p1; p += 16) {
        int sv[8];
#pragma unroll
        for (int q = 0; q < 4; q++) {
            int4 sa = *(const int4*)(psrc + p + q * 4);
            sv[2 * q]     = half ? sa.y : sa.x;
            sv[2 * q + 1] = half ? sa.w : sa.z;
        }
        uint2 hv[8];
#pragma unroll
        for (int j = 0; j < 8; j++)
            hv[j] = *(const uint2*)(hb + (size_t)sv[j] * 128 + cl * 4);
        float4 gv[8];
#pragma unroll
        for (int j = 0; j < 8; j++)
            gv[j] = pg4[p + 2 * j + half];
#pragma unroll
        for (int j = 0; j < 8; j++) {
            float g0 = gv[j].x, g1 = gv[j].y, g2 = gv[j].z;
            float f0 = blo(hv[j].x), f1 = bhi(hv[j].x), f2 = blo(hv[j].y), f3 = bhi(hv[j].y);
            a0[0] += g0 * f0; a0[1] += g0 * f1; a0[2] += g0 * f2; a0[3] += g0 * f3;
            a1[0] += g1 * f0; a1[1] += g1 * f1; a1[2] += g1 * f2; a1[3] += g1 * f3;
            a2[0] += g2 * f0; a2[1] += g2 * f1; a2[2] += g2 * f2; a2[3] += g2 * f3;
            gs0 += g0; gs1 += g1; gs2 += g2;
        }
    }
    // one masked block covers the tail (psrc/pgw padded by 16 entries)
    if (p < p1) {
        int sv[8];
#pragma unroll
        for (int q = 0; q < 4; q++) {
            int4 sa = *(const int4*)(psrc + p + q * 4);
            sv[2 * q]     = half ? sa.y : sa.x;
            sv[2 * q + 1] = half ? sa.w : sa.z;
        }
        uint2 hv[8];
#pragma unroll
        for (int j = 0; j < 8; j++)
            hv[j] = *(const uint2*)(hb + (size_t)sv[j] * 128 + cl * 4);
        float4 gv[8];
#pragma unroll
        for (int j = 0; j < 8; j++)
            gv[j] = pg4[p + 2 * j + half];
#pragma unroll
        for (int j = 0; j < 8; j++) {
            bool ok = (p + 2 * j + half) < p1;
            float g0 = ok ? gv[j].x : 0.f;
            float g1 = ok ? gv[j].y : 0.f;
            float g2 = ok ? gv[j].z : 0.f;
            float f0 = blo(hv[j].x), f1 = bhi(hv[j].x), f2 = blo(hv[j].y), f3 = bhi(hv[j].y);
            a0[0] += g0 * f0; a0[1] += g0 * f1; a0[2] += g0 * f2; a0[3] += g0 * f3;
            a1[0] += g1 * f0; a1[1] += g1 * f1; a1[2] += g1 * f2; a1[3] += g1 * f3;
            a2[0] += g2 * f0; a2[1] += g2 * f1; a2[2] += g2 * f2; a2[3] += g2 * f3;
            gs0 += g0; gs1 += g1; gs2 += g2;
        }
    }
#pragma unroll
    for (int c = 0; c < 4; c++) {
        a0[c] += __shfl_xor(a0[c], 32);
        a1[c] += __shfl_xor(a1[c], 32);
        a2[c] += __shfl_xor(a2[c], 32);
    }
    gs0 += __shfl_xor(gs0, 32);
    gs1 += __shfl_xor(gs1, 32);
    gs2 += __shfl_xor(gs2, 32);
    if (half == 0) {
        size_t base = (size_t)nid * 384 + cl * 4;
        ushort4 o0, o1, o2;
        o0.x = f2b(a0[0]); o0.y = f2b(a0[1]); o0.z = f2b(a0[2]); o0.w = f2b(a0[3]);
        o1.x = f2b(a1[0]); o1.y = f2b(a1[1]); o1.z = f2b(a1[2]); o1.w = f2b(a1[3]);
        o2.x = f2b(a2[0]); o2.y = f2b(a2[1]); o2.z = f2b(a2[2]); o2.w = f2b(a2[3]);
        *(ushort4*)(t + base)       = o0;
        *(ushort4*)(t + base + 128) = o1;
        *(ushort4*)(t + base + 256) = o2;
        if (cl == 0) {
            sk[nid * 4 + 0] = gs0;
            sk[nid * 4 + 1] = gs1;
            sk[nid * 4 + 2] = gs2;
            sk[nid * 4 + 3] = 0.f;
        }
    }
}

// ---- bf16 MFMA GEMM: out[M,128] = A[M,KD] @ Bt[128,KD]^T (+ epilogue)
//   mode 0 (embed): outB = bf16(acc + bias[col])
//   mode 1 (fc):    v = acc + sum_k sk[row,k]*bias[k*128+col]; outB=bf16(v);
//                   per-channel sum/sumsq (fp32) reduced into bnred[0:256]
__global__ __launch_bounds__(256) void gemm_mfma(const u16* __restrict__ A,
                                                 const u16* __restrict__ Bt,
                                                 int M, int KD,
                                                 const float* __restrict__ bias,
                                                 const float* __restrict__ sk,
                                                 u16* __restrict__ outB,
                                                 int mode,
                                                 float* __restrict__ bnred) {
    __shared__ u16 As[128 * 64];
    __shared__ u16 Bs[128 * 64];
    const int m0 = blockIdx.x * 128;
    const int tid = threadIdx.x;
    const int lane = tid & 63;
    const int w = tid >> 6;
    const int wr = w >> 1, wc = w & 1;

    f32x4 acc[4][4];
#pragma unroll
    for (int m = 0; m < 4; m++)
#pragma unroll
        for (int n = 0; n < 4; n++) acc[m][n] = (f32x4){0.f, 0.f, 0.f, 0.f};

    for (int k0 = 0; k0 < KD; k0 += 64) {
        __syncthreads();
#pragma unroll
        for (int i = 0; i < 4; i++) {
            int idx = tid + i * 256;
            int r = idx >> 3, g = idx & 7;
            int gs = g ^ (r & 7);
            uint4 av = make_uint4(0, 0, 0, 0);
            if (m0 + r < M) av = *(const uint4*)(A + (size_t)(m0 + r) * KD + k0 + g * 8);
            *(uint4*)(As + r * 64 + gs * 8) = av;
            uint4 bv = *(const uint4*)(Bt + (size_t)r * KD + k0 + g * 8);
            *(uint4*)(Bs + r * 64 + gs * 8) = bv;
        }
        __syncthreads();
#pragma unroll
        for (int kk = 0; kk < 2; kk++) {
            bf16x8 af[4], bfr[4];
#pragma unroll
            for (int m = 0; m < 4; m++) {
                int r = wr * 64 + m * 16 + (lane & 15);
                int g = (kk * 4 + (lane >> 4)) ^ (r & 7);
                af[m] = *(const bf16x8*)(As + r * 64 + g * 8);
            }
#pragma unroll
            for (int n = 0; n < 4; n++) {
                int r = wc * 64 + n * 16 + (lane & 15);
                int g = (kk * 4 + (lane >> 4)) ^ (r & 7);
                bfr[n] = *(const bf16x8*)(Bs + r * 64 + g * 8);
            }
#pragma unroll
            for (int m = 0; m < 4; m++)
#pragma unroll
                for (int n = 0; n < 4; n++)
                    acc[m][n] = __builtin_amdgcn_mfma_f32_16x16x32_bf16(af[m], bfr[n], acc[m][n], 0, 0, 0);
        }
    }

    if (mode == 0) {
#pragma unroll
        for (int n = 0; n < 4; n++) {
            int col = wc * 64 + n * 16 + (lane & 15);
            float bv = bias[col];
#pragma unroll
            for (int m = 0; m < 4; m++) {
#pragma unroll
                for (int j = 0; j < 4; j++) {
                    int row = m0 + wr * 64 + m * 16 + (lane >> 4) * 4 + j;
                    if (row < M) outB[(size_t)row * 128 + col] = f2b(acc[m][n][j] + bv);
                }
            }
        }
    } else {
        float colsum[4] = {0.f, 0.f, 0.f, 0.f};
        float colsq[4]  = {0.f, 0.f, 0.f, 0.f};
#pragma unroll
        for (int n = 0; n < 4; n++) {
            int col = wc * 64 + n * 16 + (lane & 15);
            float b0 = bias[col], b1 = bias[128 + col], b2 = bias[256 + col];
#pragma unroll
            for (int m = 0; m < 4; m++) {
#pragma unroll
                for (int j = 0; j < 4; j++) {
                    int row = m0 + wr * 64 + m * 16 + (lane >> 4) * 4 + j;
                    if (row < M) {
                        float4 skv = *(const float4*)(sk + row * 4);
                        float v = acc[m][n][j] + skv.x * b0 + skv.y * b1 + skv.z * b2;
                        outB[(size_t)row * 128 + col] = f2b(v);
                        colsum[n] += v;
                        colsq[n]  += v * v;
                    }
                }
            }
        }
        __syncthreads();
        float* red = (float*)As;         // 256 floats: [0:128] sum, [128:256] sq
        if (tid < 256) red[tid] = 0.f;
        __syncthreads();
#pragma unroll
        for (int n = 0; n < 4; n++) {
            float s = colsum[n], q = colsq[n];
            s += __shfl_xor(s, 16); s += __shfl_xor(s, 32);
            q += __shfl_xor(q, 16); q += __shfl_xor(q, 32);
            if (lane < 16) {
                int col = wc * 64 + n * 16 + lane;
                atomicAdd(&red[col], s);
                atomicAdd(&red[128 + col], q);
            }
        }
        __syncthreads();
        if (tid < 256) atomicAdd(&bnred[tid], red[tid]);
    }
}

// ---- hb = bf16( hb + relu((aggB-mean)*rstd*gamma + beta) )
__global__ void bn_apply(u16* __restrict__ hb,
                         const u16* __restrict__ aggB,
                         const float* __restrict__ bnred,
                         const float* __restrict__ gamma, const float* __restrict__ beta,
                         float invN, int N) {
    int idx = blockIdx.x * 256 + threadIdx.x;   // 4-channel group index
    if (idx >= N * 32) return;
    int c4 = idx & 31;
    float4 s  = *(const float4*)(bnred + c4 * 4);
    float4 q  = *(const float4*)(bnred + 128 + c4 * 4);
    float4 ga = *(const float4*)(gamma + c4 * 4);
    float4 be = *(const float4*)(beta + c4 * 4);
    float4 sc, sh;
    {
        float m, v2;
        m = s.x * invN; v2 = q.x * invN - m * m; sc.x = ga.x * rsqrtf(v2 + 1e-5f); sh.x = be.x - m * sc.x;
        m = s.y * invN; v2 = q.y * invN - m * m; sc.y = ga.y * rsqrtf(v2 + 1e-5f); sh.y = be.y - m * sc.y;
        m = s.z * invN; v2 = q.z * invN - m * m; sc.z = ga.z * rsqrtf(v2 + 1e-5f); sh.z = be.z - m * sc.z;
        m = s.w * invN; v2 = q.w * invN - m * m; sc.w = ga.w * rsqrtf(v2 + 1e-5f); sh.w = be.w - m * sc.w;
    }
    uint2 av = ((const uint2*)aggB)[idx];
    uint2 hv = ((const uint2*)hb)[idx];
    float r0 = blo(hv.x) + fmaxf(blo(av.x) * sc.x + sh.x, 0.f);
    float r1 = bhi(hv.x) + fmaxf(bhi(av.x) * sc.y + sh.y, 0.f);
    float r2 = blo(hv.y) + fmaxf(blo(av.y) * sc.z + sh.z, 0.f);
    float r3 = bhi(hv.y) + fmaxf(bhi(av.y) * sc.w + sh.w, 0.f);
    uint2 o;
    o.x = (u32)f2b(r0) | ((u32)f2b(r1) << 16);
    o.y = (u32)f2b(r2) | ((u32)f2b(r3) << 16);
    ((uint2*)hb)[idx] = o;
}

// ---- per-graph sums from bf16 h: 25 rows per block (graph_ids sorted)
__global__ void readout_kernel(const u16* __restrict__ hb, const int* __restrict__ gids,
                               float* __restrict__ hg, float* __restrict__ cnts, int N) {
    int c = threadIdx.x;    // 128 channels
    int r0 = blockIdx.x * 25;
    if (r0 >= N) return;
    int r1 = min(r0 + 25, N);
    int cur = gids[r0];
    float acc = 0.f, cnt = 0.f;
    for (int r = r0; r < r1; r++) {
        int g = gids[r];
        if (g != cur) {
            atomicAdd(&hg[(size_t)cur * 128 + c], acc);
            if (c == 0) atomicAdd(&cnts[cur], cnt);
            acc = 0.f; cnt = 0.f; cur = g;
        }
        acc += blo((u32)hb[(size_t)r * 128 + c]);
        cnt += 1.f;
    }
    atomicAdd(&hg[(size_t)cur * 128 + c], acc);
    if (c == 0) atomicAdd(&cnts[cur], cnt);
}

// ---- MLP readout
__global__ void mlp_kernel(const float* __restrict__ hg, const float* __restrict__ cnts,
                           const float* __restrict__ W1, const float* __restrict__ b1,
                           const float* __restrict__ W2, const float* __restrict__ b2,
                           const float* __restrict__ W3, const float* __restrict__ b3,
                           float* __restrict__ out) {
    __shared__ float v[128], y1[64], y2[32];
    int g = blockIdx.x, t = threadIdx.x;
    float inv = 1.0f / cnts[g];
    v[t] = hg[(size_t)g * 128 + t] * inv;
    __syncthreads();
    if (t < 64) {
        float a = b1[t];
        for (int k = 0; k < 128; k++) a += v[k] * W1[k * 64 + t];
        y1[t] = fmaxf(a, 0.f);
    }
    __syncthreads();
    if (t < 32) {
        float a = b2[t];
        for (int k = 0; k < 64; k++) a += y1[k] * W2[k * 32 + t];
        y2[t] = fmaxf(a, 0.f);
    }
    __syncthreads();
    if (t < 10) {
        float a = b3[t];
        for (int k = 0; k < 32; k++) a += y2[k] * W3[k * 10 + t];
        out[g * 10 + t] = a;
    }
}

extern "C" void kernel_launch(void* const* d_in, const int* in_sizes, int n_in,
                              void* d_out, int out_size, void* d_ws, size_t ws_size,
                              hipStream_t stream) {
    const float* x      = (const float*)d_in[0];
    const float* emb_W  = (const float*)d_in[1];
    const float* emb_b  = (const float*)d_in[2];
    const float* fc_W   = (const float*)d_in[3];
    const float* fc_b   = (const float*)d_in[4];
    const float* mu     = (const float*)d_in[5];
    const float* isig   = (const float*)d_in[6];
    const float* gamma  = (const float*)d_in[7];
    const float* beta   = (const float*)d_in[8];
    const float* ppW    = (const float*)d_in[9];
    const float* ppb    = (const float*)d_in[10];
    const float* W1     = (const float*)d_in[11];
    const float* b1     = (const float*)d_in[12];
    const float* W2     = (const float*)d_in[13];
    const float* b2     = (const float*)d_in[14];
    const float* W3     = (const float*)d_in[15];
    const float* b3     = (const float*)d_in[16];
    const int*   src    = (const int*)d_in[17];
    const int*   dst    = (const int*)d_in[18];
    const int*   gids   = (const int*)d_in[19];

    const int N = in_sizes[0] / 128;
    const int E = in_sizes[17];
    const int L = in_sizes[8] / 128;
    const int G = out_size / 10;
    const int npg = N / G;                 // 1000
    const int Epad = E + 16;
    float* out = (float*)d_out;

    char* wp = (char*)d_ws;
    auto alloc = [&](size_t bytes) {
        char* p = wp;
        wp += (bytes + 255) & ~(size_t)255;
        return (void*)p;
    };
    u16*   hb     = (u16*)alloc((size_t)N * 128 * 2);
    u16*   t      = (u16*)alloc((size_t)N * 384 * 2);
    u16*   aggB   = (u16*)alloc((size_t)N * 128 * 2);
    float* pgw    = (float*)alloc((size_t)L * Epad * 16);
    int*   psrc   = (int*)alloc((size_t)Epad * 4);
    int*   pdst   = (int*)alloc((size_t)E * 4);
    u32*   tmp    = (u32*)alloc((size_t)E * 4);
    float* sk     = (float*)alloc((size_t)N * 4 * 4);
    int*   cnt    = (int*)alloc((size_t)N * 4);
    int*   rs     = (int*)alloc((size_t)(N + 1) * 4);
    int*   gcur   = (int*)alloc(256 * 4);
    int*   bsum   = (int*)alloc(256 * 4);
    int*   boff   = (int*)alloc(256 * 4);
    u16*   wembt  = (u16*)alloc((size_t)128 * 128 * 2);
    u16*   wfct   = (u16*)alloc((size_t)L * 128 * 384 * 2);
    float* bnAll  = (float*)alloc((size_t)L * 256 * 4);
    float* hg     = (float*)alloc((size_t)G * 128 * 4);
    float* cnts   = (float*)alloc((size_t)G * 4);
    u16*   xb     = (u16*)t;   // overlay: xb only needed before first agg

    hipMemsetAsync(cnt, 0, (size_t)N * 4, stream);
    hipMemsetAsync(gcur, 0, 256 * 4, stream);
    hipMemsetAsync(hg, 0, (size_t)G * 128 * 4, stream);
    hipMemsetAsync(cnts, 0, (size_t)G * 4, stream);
    hipMemsetAsync(bnAll, 0, (size_t)L * 256 * 4, stream);
    hipMemsetAsync(psrc + E, 0, 16 * 4, stream);   // zero pad (safe gather idx)

    // conversions + weight prep
    cvt_bf16<<<(N * 32 + 255) / 256, 256, 0, stream>>>(x, xb, N * 32);
    prep_embW<<<(128 * 128 + 255) / 256, 256, 0, stream>>>(emb_W, wembt);
    prep_fcW<<<(L * 128 * 384 + 255) / 256, 256, 0, stream>>>(fc_W, wfct, L * 128 * 384);

    // CSR build: hist -> scan -> graph-bucket passes
    const int nb = (N + 255) / 256;
    hist_kernel<<<(E + 255) / 256, 256, 0, stream>>>(dst, cnt, E);
    scan_partial<<<nb, 256, 0, stream>>>(cnt, bsum, N);
    scan_bsums<<<1, 256, 0, stream>>>(bsum, boff, nb);
    scan_final<<<nb, 256, 0, stream>>>(cnt, boff, rs, N);
    bucketA<<<(E + 4095) / 4096, 256, 0, stream>>>(src, dst, rs, gcur, tmp, E, npg, G);
    bucketB<<<G, 1024, 0, stream>>>(tmp, rs, psrc, npg);
    fill_pdst<<<(N + 3) / 4, 256, 0, stream>>>(rs, pdst, N);
    gw_kernel<<<(E + 255) / 256, 256, 0, stream>>>(psrc, pdst, cnt, ppW, ppb, mu, isig,
                                                   pgw, E, Epad, L);

    // node embedding
    const int gblocks = (N + 127) / 128;
    gemm_mfma<<<gblocks, 256, 0, stream>>>(xb, wembt, N, 128, emb_b, nullptr, hb, 0, nullptr);

    // agg grid: 8 XCD lanes x (graphs-per-xcd * blocks-per-graph)
    const int bpg = npg / 4;                       // blocks per graph (4 nodes/block)
    const int agg_grid = 8 * ((G + 7) / 8) * bpg;
    const float invN = 1.0f / (float)N;
    for (int l = 0; l < L; l++) {
        agg_kernel<<<agg_grid, 256, 0, stream>>>(hb, pgw + (size_t)l * Epad * 4, psrc, rs,
                                                 t, sk, npg, bpg, G);
        gemm_mfma<<<gblocks, 256, 0, stream>>>(t, wfct + (size_t)l * 128 * 384, N, 384,
                                               fc_b + (size_t)l * 384, sk, aggB, 1,
                                               bnAll + (size_t)l * 256);
        bn_apply<<<(N * 32 + 255) / 256, 256, 0, stream>>>(hb, aggB, bnAll + (size_t)l * 256,
                                                           gamma + l * 128, beta + l * 128, invN, N);
    }

    readout_kernel<<<(N + 24) / 25, 128, 0, stream>>>(hb, gids, hg, cnts, N);
    mlp_kernel<<<G, 128, 0, stream>>>(hg, cnts, W1, b1, W2, b2, W3, b3, out);
}

// Round 10
// 488.420 us; speedup vs baseline: 1.1051x; 1.1051x over previous
//
#include <hip/hip_runtime.h>

// ---------------------------------------------------------------------------
// MoNet GNN: N=50000, E=800000, H=128, K=3, L=4, pdim=2, G=50, npg=1000
// Round 10: agg = R6 structure (best measured: 16-edge unmasked main loop,
//           psrc int4 + float4 f32 gw, no XCD swizzle) + masked 8-edge
//           remainder (<=2 iters, 4 gathers in flight) replacing the serial
//           2-edge tail. cvt_bf16 fused into embed GEMM staging; fill_pdst
//           folded into bucketB. bf16 h, bucketed CSR, BN fused in epilogue.
// ---------------------------------------------------------------------------

typedef unsigned char  u8;
typedef unsigned short u16;
typedef unsigned int   u32;
typedef __attribute__((ext_vector_type(8))) short bf16x8;
typedef __attribute__((ext_vector_type(4))) float f32x4;

__device__ __forceinline__ u16 f2b(float f) {
    union { float f; u32 u; } v; v.f = f;
    u32 u = v.u;
    u32 r = (u + 0x7fffu + ((u >> 16) & 1u)) >> 16;   // RNE
    return (u16)r;
}
__device__ __forceinline__ float blo(u32 h) {
    union { u32 u; float f; } v; v.u = h << 16; return v.f;
}
__device__ __forceinline__ float bhi(u32 h) {
    union { u32 u; float f; } v; v.u = h & 0xffff0000u; return v.f;
}

// ---- prep emb_W^T in bf16: Bt[n][k] = emb_W[k*128+n]
__global__ void prep_embW(const float* __restrict__ W, u16* __restrict__ Bt) {
    int idx = blockIdx.x * 256 + threadIdx.x;   // 16384
    int n = idx >> 7, k = idx & 127;
    Bt[idx] = f2b(W[k * 128 + n]);
}

// ---- prep fc weights: Bp[l][n][kc*128+r] = fcW[l][r][kc*128+n]  (bf16, B^T)
__global__ void prep_fcW(const float* __restrict__ W, u16* __restrict__ Bp, int total) {
    int idx = blockIdx.x * 256 + threadIdx.x;   // L*128*384
    if (idx >= total) return;
    int kk = idx % 384;
    int rest = idx / 384;
    int n = rest & 127;
    int l = rest >> 7;
    int kc = kk >> 7, r = kk & 127;
    Bp[idx] = f2b(W[((size_t)(l * 128 + r)) * 384 + kc * 128 + n]);
}

// ---- in-degree histogram
__global__ void hist_kernel(const int* __restrict__ dst, int* __restrict__ cnt, int E) {
    int e = blockIdx.x * 256 + threadIdx.x;
    if (e < E) atomicAdd(&cnt[dst[e]], 1);
}

// ---- 3-phase exclusive scan of cnt[N] -> rs[N+1]
__global__ void scan_partial(const int* __restrict__ cnt, int* __restrict__ bsum, int N) {
    __shared__ int buf[256];
    int t = threadIdx.x, base = blockIdx.x * 256;
    buf[t] = (base + t < N) ? cnt[base + t] : 0;
    __syncthreads();
    for (int off = 128; off > 0; off >>= 1) {
        if (t < off) buf[t] += buf[t + off];
        __syncthreads();
    }
    if (t == 0) bsum[blockIdx.x] = buf[0];
}
__global__ void scan_bsums(const int* __restrict__ bsum, int* __restrict__ boff, int nb) {
    __shared__ int buf[256];
    int t = threadIdx.x;
    int v = (t < nb) ? bsum[t] : 0;
    buf[t] = v;
    __syncthreads();
    for (int off = 1; off < 256; off <<= 1) {
        int x = (t >= off) ? buf[t - off] : 0;
        __syncthreads();
        buf[t] += x;
        __syncthreads();
    }
    if (t < nb) boff[t] = buf[t] - v;   // exclusive
}
__global__ void scan_final(const int* __restrict__ cnt, const int* __restrict__ boff,
                           int* __restrict__ rs, int N) {
    __shared__ int buf[256];
    int t = threadIdx.x, base = blockIdx.x * 256;
    int v = (base + t < N) ? cnt[base + t] : 0;
    buf[t] = v;
    __syncthreads();
    for (int off = 1; off < 256; off <<= 1) {
        int x = (t >= off) ? buf[t - off] : 0;
        __syncthreads();
        buf[t] += x;
        __syncthreads();
    }
    if (base + t < N) rs[base + t + 1] = boff[blockIdx.x] + buf[t];
    if (base == 0 && t == 0) rs[0] = 0;
}

// ---- Pass A: bin 4096 edges per block by graph (LDS), chunk-copy to tmp
__global__ __launch_bounds__(256) void bucketA(const int* __restrict__ src,
                                               const int* __restrict__ dst,
                                               const int* __restrict__ rs,
                                               int* __restrict__ gcur,
                                               u32* __restrict__ tmp,
                                               int E, int npg, int G) {
    __shared__ u32 ebuf[4096];
    __shared__ u8  gmap[4096];
    __shared__ int ghist[64], gexc[64], gbase[64], lcur[64];
    const int tid = threadIdx.x;
    const int e0 = blockIdx.x * 4096;
    const int n = min(4096, E - e0);
    if (tid < 64) { ghist[tid] = 0; lcur[tid] = 0; }
    __syncthreads();
    for (int i = tid; i < n; i += 256) {
        int g = dst[e0 + i] / npg;
        atomicAdd(&ghist[g], 1);
    }
    __syncthreads();
    if (tid == 0) {
        int acc = 0;
        for (int g = 0; g < G; g++) { gexc[g] = acc; acc += ghist[g]; }
    }
    __syncthreads();
    if (tid < G) {
        int c = ghist[tid];
        gbase[tid] = (c > 0) ? rs[tid * npg] + atomicAdd(&gcur[tid], c) : 0;
    }
    __syncthreads();
    for (int i = tid; i < n; i += 256) {
        int d = dst[e0 + i];
        int g = d / npg;
        int pos = gexc[g] + atomicAdd(&lcur[g], 1);
        ebuf[pos] = ((u32)src[e0 + i] << 16) | (u32)(d - g * npg);
        gmap[pos] = (u8)g;
    }
    __syncthreads();
    for (int i = tid; i < n; i += 256) {
        int g = gmap[i];
        tmp[gbase[g] + (i - gexc[g])] = ebuf[i];
    }
}

// ---- Pass B: one block per graph: counting-scatter psrc via LDS cursors,
//      then fill pdst from the LDS row offsets (fused fill_pdst).
__global__ __launch_bounds__(1024) void bucketB(const u32* __restrict__ tmp,
                                                const int* __restrict__ rs,
                                                int* __restrict__ psrc,
                                                int* __restrict__ pdst,
                                                int npg) {
    __shared__ int rsl[1025];
    __shared__ int lcur[1024];
    const int g = blockIdx.x, tid = threadIdx.x;
    const int base = g * npg;
    for (int i = tid; i <= npg; i += 1024) rsl[i] = rs[base + i];
    for (int i = tid; i < npg; i += 1024) lcur[i] = 0;
    __syncthreads();
    const int p0 = rsl[0], p1 = rsl[npg];
    for (int p = p0 + tid; p < p1; p += 1024) {
        u32 v = tmp[p];
        int dl = v & 0xffffu;
        int pos = rsl[dl] + atomicAdd(&lcur[dl], 1);
        psrc[pos] = (int)(v >> 16);
    }
    // fill pdst (independent of the scatter above; no sync needed)
    for (int i = tid; i < npg; i += 1024) {
        int a = rsl[i], b = rsl[i + 1];
        for (int p = a; p < b; p++) pdst[p] = base + i;
    }
}

// ---- Gaussian weights in permuted order, all L layers, padded float4
//      layer stride Epad for safe masked over-read in agg
__global__ void gw_kernel(const int* __restrict__ psrc, const int* __restrict__ pdst,
                          const int* __restrict__ cnt,
                          const float* __restrict__ ppW, const float* __restrict__ ppb,
                          const float* __restrict__ mu, const float* __restrict__ isig,
                          float* __restrict__ pgw, int E, int Epad, int L) {
    int p = blockIdx.x * 256 + threadIdx.x;
    if (p >= E) return;
    float ps0 = rsqrtf((float)cnt[psrc[p]] + 1.0f);
    float ps1 = rsqrtf((float)cnt[pdst[p]] + 1.0f);
    for (int l = 0; l < L; l++) {
        float p0 = tanhf(ps0 * ppW[l * 4 + 0] + ps1 * ppW[l * 4 + 2] + ppb[l * 2 + 0]);
        float p1 = tanhf(ps0 * ppW[l * 4 + 1] + ps1 * ppW[l * 4 + 3] + ppb[l * 2 + 1]);
        float4 o;
        float* ov = (float*)&o;
#pragma unroll
        for (int k = 0; k < 3; k++) {
            float d0 = (p0 - mu[(l * 3 + k) * 2 + 0]) * isig[(l * 3 + k) * 2 + 0];
            float d1 = (p1 - mu[(l * 3 + k) * 2 + 1]) * isig[(l * 3 + k) * 2 + 1];
            ov[k] = expf(-0.5f * (d0 * d0 + d1 * d1));
        }
        o.w = 0.f;
        ((float4*)pgw)[(size_t)l * Epad + p] = o;
    }
}

// ---- per-node aggregation (R6 structure + masked-8 remainder).
//      One wave per node; lanes 0-31 even edge of pair, 32-63 odd; 4 bf16
//      channels per lane via uint2 gather. Main: unmasked 16-edge blocks.
//      Tail: masked 8-edge blocks (<=2 iters, 4 gathers in flight).
__global__ __launch_bounds__(256) void agg_kernel(const u16* __restrict__ hb,
                                                  const float* __restrict__ pgw,   // layer base
                                                  const int* __restrict__ psrc,
                                                  const int* __restrict__ rs,
                                                  u16* __restrict__ t,
                                                  float* __restrict__ sk, int N) {
    int nid = blockIdx.x * 4 + (threadIdx.x >> 6);
    if (nid >= N) return;
    int lane = threadIdx.x & 63;
    int half = lane >> 5;
    int cl = lane & 31;
    int p0 = __builtin_amdgcn_readfirstlane(rs[nid]);
    int p1 = __builtin_amdgcn_readfirstlane(rs[nid + 1]);
    float a0[4] = {}, a1[4] = {}, a2[4] = {};
    float gs0 = 0.f, gs1 = 0.f, gs2 = 0.f;
    const float4* pg4 = (const float4*)pgw;
    int p = p0;
    // unmasked 16-edge blocks (8 gathers in flight)
    for (; p + 16 <= p1; p += 16) {
        int sv[8];
#pragma unroll
        for (int q = 0; q < 4; q++) {
            int4 sa = *(const int4*)(psrc + p + q * 4);
            sv[2 * q]     = half ? sa.y : sa.x;
            sv[2 * q + 1] = half ? sa.w : sa.z;
        }
        uint2 hv[8];
#pragma unroll
        for (int j = 0; j < 8; j++)
            hv[j] = *(const uint2*)(hb + (size_t)sv[j] * 128 + cl * 4);
        float4 gv[8];
#pragma unroll
        for (int j = 0; j < 8; j++)
            gv[j] = pg4[p + 2 * j + half];
#pragma unroll
        for (int j = 0; j < 8; j++) {
            float g0 = gv[j].x, g1 = gv[j].y, g2 = gv[j].z;
            float f0 = blo(hv[j].x), f1 = bhi(hv[j].x), f2 = blo(hv[j].y), f3 = bhi(hv[j].y);
            a0[0] += g0 * f0; a0[1] += g0 * f1; a0[2] += g0 * f2; a0[3] += g0 * f3;
            a1[0] += g1 * f0; a1[1] += g1 * f1; a1[2] += g1 * f2; a1[3] += g1 * f3;
            a2[0] += g2 * f0; a2[1] += g2 * f1; a2[2] += g2 * f2; a2[3] += g2 * f3;
            gs0 += g0; gs1 += g1; gs2 += g2;
        }
    }
    // masked 8-edge blocks for the tail (<=2 iterations; streams padded)
    for (; p < p1; p += 8) {
        int4 sa = *(const int4*)(psrc + p);
        int4 sb = *(const int4*)(psrc + p + 4);
        int sv[4] = { half ? sa.y : sa.x, half ? sa.w : sa.z,
                      half ? sb.y : sb.x, half ? sb.w : sb.z };
        uint2 hv[4];
#pragma unroll
        for (int j = 0; j < 4; j++)
            hv[j] = *(const uint2*)(hb + (size_t)sv[j] * 128 + cl * 4);
        float4 gv[4];
#pragma unroll
        for (int j = 0; j < 4; j++)
            gv[j] = pg4[p + 2 * j + half];
#pragma unroll
        for (int j = 0; j < 4; j++) {
            bool ok = (p + 2 * j + half) < p1;
            float g0 = ok ? gv[j].x : 0.f;
            float g1 = ok ? gv[j].y : 0.f;
            float g2 = ok ? gv[j].z : 0.f;
            float f0 = blo(hv[j].x), f1 = bhi(hv[j].x), f2 = blo(hv[j].y), f3 = bhi(hv[j].y);
            a0[0] += g0 * f0; a0[1] += g0 * f1; a0[2] += g0 * f2; a0[3] += g0 * f3;
            a1[0] += g1 * f0; a1[1] += g1 * f1; a1[2] += g1 * f2; a1[3] += g1 * f3;
            a2[0] += g2 * f0; a2[1] += g2 * f1; a2[2] += g2 * f2; a2[3] += g2 * f3;
            gs0 += g0; gs1 += g1; gs2 += g2;
        }
    }
#pragma unroll
    for (int c = 0; c < 4; c++) {
        a0[c] += __shfl_xor(a0[c], 32);
        a1[c] += __shfl_xor(a1[c], 32);
        a2[c] += __shfl_xor(a2[c], 32);
    }
    gs0 += __shfl_xor(gs0, 32);
    gs1 += __shfl_xor(gs1, 32);
    gs2 += __shfl_xor(gs2, 32);
    if (half == 0) {
        size_t base = (size_t)nid * 384 + cl * 4;
        ushort4 o0, o1, o2;
        o0.x = f2b(a0[0]); o0.y = f2b(a0[1]); o0.z = f2b(a0[2]); o0.w = f2b(a0[3]);
        o1.x = f2b(a1[0]); o1.y = f2b(a1[1]); o1.z = f2b(a1[2]); o1.w = f2b(a1[3]);
        o2.x = f2b(a2[0]); o2.y = f2b(a2[1]); o2.z = f2b(a2[2]); o2.w = f2b(a2[3]);
        *(ushort4*)(t + base)       = o0;
        *(ushort4*)(t + base + 128) = o1;
        *(ushort4*)(t + base + 256) = o2;
        if (cl == 0) {
            sk[nid * 4 + 0] = gs0;
            sk[nid * 4 + 1] = gs1;
            sk[nid * 4 + 2] = gs2;
            sk[nid * 4 + 3] = 0.f;
        }
    }
}

// ---- bf16 MFMA GEMM: out[M,128] = A[M,KD] @ Bt[128,KD]^T (+ epilogue)
//   mode 0 (embed): A is fp32 (converted to bf16 during LDS staging);
//                   outB = bf16(acc + bias[col])
//   mode 1 (fc):    A is bf16; v = acc + sum_k sk[row,k]*bias[k*128+col];
//                   outB=bf16(v); per-channel sum/sumsq -> bnred[0:256]
__global__ __launch_bounds__(256) void gemm_mfma(const void* __restrict__ Araw,
                                                 const u16* __restrict__ Bt,
                                                 int M, int KD,
                                                 const float* __restrict__ bias,
                                                 const float* __restrict__ sk,
                                                 u16* __restrict__ outB,
                                                 int mode,
                                                 float* __restrict__ bnred) {
    __shared__ u16 As[128 * 64];
    __shared__ u16 Bs[128 * 64];
    const int m0 = blockIdx.x * 128;
    const int tid = threadIdx.x;
    const int lane = tid & 63;
    const int w = tid >> 6;
    const int wr = w >> 1, wc = w & 1;

    f32x4 acc[4][4];
#pragma unroll
    for (int m = 0; m < 4; m++)
#pragma unroll
        for (int n = 0; n < 4; n++) acc[m][n] = (f32x4){0.f, 0.f, 0.f, 0.f};

    for (int k0 = 0; k0 < KD; k0 += 64) {
        __syncthreads();
#pragma unroll
        for (int i = 0; i < 4; i++) {
            int idx = tid + i * 256;
            int r = idx >> 3, g = idx & 7;
            int gs = g ^ (r & 7);
            uint4 av = make_uint4(0, 0, 0, 0);
            if (mode == 0) {
                // fp32 source: read 8 floats, convert to 8 bf16
                const float* Af = (const float*)Araw;
                if (m0 + r < M) {
                    float4 v0 = *(const float4*)(Af + (size_t)(m0 + r) * KD + k0 + g * 8);
                    float4 v1 = *(const float4*)(Af + (size_t)(m0 + r) * KD + k0 + g * 8 + 4);
                    av.x = (u32)f2b(v0.x) | ((u32)f2b(v0.y) << 16);
                    av.y = (u32)f2b(v0.z) | ((u32)f2b(v0.w) << 16);
                    av.z = (u32)f2b(v1.x) | ((u32)f2b(v1.y) << 16);
                    av.w = (u32)f2b(v1.z) | ((u32)f2b(v1.w) << 16);
                }
            } else {
                const u16* Ab = (const u16*)Araw;
                if (m0 + r < M) av = *(const uint4*)(Ab + (size_t)(m0 + r) * KD + k0 + g * 8);
            }
            *(uint4*)(As + r * 64 + gs * 8) = av;
            uint4 bv = *(const uint4*)(Bt + (size_t)r * KD + k0 + g * 8);
            *(uint4*)(Bs + r * 64 + gs * 8) = bv;
        }
        __syncthreads();
#pragma unroll
        for (int kk = 0; kk < 2; kk++) {
            bf16x8 af[4], bfr[4];
#pragma unroll
            for (int m = 0; m < 4; m++) {
                int r = wr * 64 + m * 16 + (lane & 15);
                int g = (kk * 4 + (lane >> 4)) ^ (r & 7);
                af[m] = *(const bf16x8*)(As + r * 64 + g * 8);
            }
#pragma unroll
            for (int n = 0; n < 4; n++) {
                int r = wc * 64 + n * 16 + (lane & 15);
                int g = (kk * 4 + (lane >> 4)) ^ (r & 7);
                bfr[n] = *(const bf16x8*)(Bs + r * 64 + g * 8);
            }
#pragma unroll
            for (int m = 0; m < 4; m++)
#pragma unroll
                for (int n = 0; n < 4; n++)
                    acc[m][n] = __builtin_amdgcn_mfma_f32_16x16x32_bf16(af[m], bfr[n], acc[m][n], 0, 0, 0);
        }
    }

    if (mode == 0) {
#pragma unroll
        for (int n = 0; n < 4; n++) {
            int col = wc * 64 + n * 16 + (lane & 15);
            float bv = bias[col];
#pragma unroll
            for (int m = 0; m < 4; m++) {
#pragma unroll
                for (int j = 0; j < 4; j++) {
                    int row = m0 + wr * 64 + m * 16 + (lane >> 4) * 4 + j;
                    if (row < M) outB[(size_t)row * 128 + col] = f2b(acc[m][n][j] + bv);
                }
            }
        }
    } else {
        float colsum[4] = {0.f, 0.f, 0.f, 0.f};
        float colsq[4]  = {0.f, 0.f, 0.f, 0.f};
#pragma unroll
        for (int n = 0; n < 4; n++) {
            int col = wc * 64 + n * 16 + (lane & 15);
            float b0 = bias[col], b1 = bias[128 + col], b2 = bias[256 + col];
#pragma unroll
            for (int m = 0; m < 4; m++) {
#pragma unroll
                for (int j = 0; j < 4; j++) {
                    int row = m0 + wr * 64 + m * 16 + (lane >> 4) * 4 + j;
                    if (row < M) {
                        float4 skv = *(const float4*)(sk + row * 4);
                        float v = acc[m][n][j] + skv.x * b0 + skv.y * b1 + skv.z * b2;
                        outB[(size_t)row * 128 + col] = f2b(v);
                        colsum[n] += v;
                        colsq[n]  += v * v;
                    }
                }
            }
        }
        __syncthreads();
        float* red = (float*)As;         // 256 floats: [0:128] sum, [128:256] sq
        if (tid < 256) red[tid] = 0.f;
        __syncthreads();
#pragma unroll
        for (int n = 0; n < 4; n++) {
            float s = colsum[n], q = colsq[n];
            s += __shfl_xor(s, 16); s += __shfl_xor(s, 32);
            q += __shfl_xor(q, 16); q += __shfl_xor(q, 32);
            if (lane < 16) {
                int col = wc * 64 + n * 16 + lane;
                atomicAdd(&red[col], s);
                atomicAdd(&red[128 + col], q);
            }
        }
        __syncthreads();
        if (tid < 256) atomicAdd(&bnred[tid], red[tid]);
    }
}

// ---- hb = bf16( hb + relu((aggB-mean)*rstd*gamma + beta) )
__global__ void bn_apply(u16* __restrict__ hb,
                         const u16* __restrict__ aggB,
                         const float* __restrict__ bnred,
                         const float* __restrict__ gamma, const float* __restrict__ beta,
                         float invN, int N) {
    int idx = blockIdx.x * 256 + threadIdx.x;   // 4-channel group index
    if (idx >= N * 32) return;
    int c4 = idx & 31;
    float4 s  = *(const float4*)(bnred + c4 * 4);
    float4 q  = *(const float4*)(bnred + 128 + c4 * 4);
    float4 ga = *(const float4*)(gamma + c4 * 4);
    float4 be = *(const float4*)(beta + c4 * 4);
    float4 sc, sh;
    {
        float m, v2;
        m = s.x * invN; v2 = q.x * invN - m * m; sc.x = ga.x * rsqrtf(v2 + 1e-5f); sh.x = be.x - m * sc.x;
        m = s.y * invN; v2 = q.y * invN - m * m; sc.y = ga.y * rsqrtf(v2 + 1e-5f); sh.y = be.y - m * sc.y;
        m = s.z * invN; v2 = q.z * invN - m * m; sc.z = ga.z * rsqrtf(v2 + 1e-5f); sh.z = be.z - m * sc.z;
        m = s.w * invN; v2 = q.w * invN - m * m; sc.w = ga.w * rsqrtf(v2 + 1e-5f); sh.w = be.w - m * sc.w;
    }
    uint2 av = ((const uint2*)aggB)[idx];
    uint2 hv = ((const uint2*)hb)[idx];
    float r0 = blo(hv.x) + fmaxf(blo(av.x) * sc.x + sh.x, 0.f);
    float r1 = bhi(hv.x) + fmaxf(bhi(av.x) * sc.y + sh.y, 0.f);
    float r2 = blo(hv.y) + fmaxf(blo(av.y) * sc.z + sh.z, 0.f);
    float r3 = bhi(hv.y) + fmaxf(bhi(av.y) * sc.w + sh.w, 0.f);
    uint2 o;
    o.x = (u32)f2b(r0) | ((u32)f2b(r1) << 16);
    o.y = (u32)f2b(r2) | ((u32)f2b(r3) << 16);
    ((uint2*)hb)[idx] = o;
}

// ---- per-graph sums from bf16 h: 25 rows per block (graph_ids sorted)
__global__ void readout_kernel(const u16* __restrict__ hb, const int* __restrict__ gids,
                               float* __restrict__ hg, float* __restrict__ cnts, int N) {
    int c = threadIdx.x;    // 128 channels
    int r0 = blockIdx.x * 25;
    if (r0 >= N) return;
    int r1 = min(r0 + 25, N);
    int cur = gids[r0];
    float acc = 0.f, cnt = 0.f;
    for (int r = r0; r < r1; r++) {
        int g = gids[r];
        if (g != cur) {
            atomicAdd(&hg[(size_t)cur * 128 + c], acc);
            if (c == 0) atomicAdd(&cnts[cur], cnt);
            acc = 0.f; cnt = 0.f; cur = g;
        }
        acc += blo((u32)hb[(size_t)r * 128 + c]);
        cnt += 1.f;
    }
    atomicAdd(&hg[(size_t)cur * 128 + c], acc);
    if (c == 0) atomicAdd(&cnts[cur], cnt);
}

// ---- MLP readout
__global__ void mlp_kernel(const float* __restrict__ hg, const float* __restrict__ cnts,
                           const float* __restrict__ W1, const float* __restrict__ b1,
                           const float* __restrict__ W2, const float* __restrict__ b2,
                           const float* __restrict__ W3, const float* __restrict__ b3,
                           float* __restrict__ out) {
    __shared__ float v[128], y1[64], y2[32];
    int g = blockIdx.x, t = threadIdx.x;
    float inv = 1.0f / cnts[g];
    v[t] = hg[(size_t)g * 128 + t] * inv;
    __syncthreads();
    if (t < 64) {
        float a = b1[t];
        for (int k = 0; k < 128; k++) a += v[k] * W1[k * 64 + t];
        y1[t] = fmaxf(a, 0.f);
    }
    __syncthreads();
    if (t < 32) {
        float a = b2[t];
        for (int k = 0; k < 64; k++) a += y1[k] * W2[k * 32 + t];
        y2[t] = fmaxf(a, 0.f);
    }
    __syncthreads();
    if (t < 10) {
        float a = b3[t];
        for (int k = 0; k < 32; k++) a += y2[k] * W3[k * 10 + t];
        out[g * 10 + t] = a;
    }
}

extern "C" void kernel_launch(void* const* d_in, const int* in_sizes, int n_in,
                              void* d_out, int out_size, void* d_ws, size_t ws_size,
                              hipStream_t stream) {
    const float* x      = (const float*)d_in[0];
    const float* emb_W  = (const float*)d_in[1];
    const float* emb_b  = (const float*)d_in[2];
    const float* fc_W   = (const float*)d_in[3];
    const float* fc_b   = (const float*)d_in[4];
    const float* mu     = (const float*)d_in[5];
    const float* isig   = (const float*)d_in[6];
    const float* gamma  = (const float*)d_in[7];
    const float* beta   = (const float*)d_in[8];
    const float* ppW    = (const float*)d_in[9];
    const float* ppb    = (const float*)d_in[10];
    const float* W1     = (const float*)d_in[11];
    const float* b1     = (const float*)d_in[12];
    const float* W2     = (const float*)d_in[13];
    const float* b2     = (const float*)d_in[14];
    const float* W3     = (const float*)d_in[15];
    const float* b3     = (const float*)d_in[16];
    const int*   src    = (const int*)d_in[17];
    const int*   dst    = (const int*)d_in[18];
    const int*   gids   = (const int*)d_in[19];

    const int N = in_sizes[0] / 128;
    const int E = in_sizes[17];
    const int L = in_sizes[8] / 128;
    const int G = out_size / 10;
    const int npg = N / G;                 // 1000
    const int Epad = E + 16;
    float* out = (float*)d_out;

    char* wp = (char*)d_ws;
    auto alloc = [&](size_t bytes) {
        char* p = wp;
        wp += (bytes + 255) & ~(size_t)255;
        return (void*)p;
    };
    u16*   hb     = (u16*)alloc((size_t)N * 128 * 2);
    u16*   t      = (u16*)alloc((size_t)N * 384 * 2);
    u16*   aggB   = (u16*)alloc((size_t)N * 128 * 2);
    float* pgw    = (float*)alloc((size_t)L * Epad * 16);
    int*   psrc   = (int*)alloc((size_t)Epad * 4);
    int*   pdst   = (int*)alloc((size_t)E * 4);
    u32*   tmp    = (u32*)alloc((size_t)E * 4);
    float* sk     = (float*)alloc((size_t)N * 4 * 4);
    int*   cnt    = (int*)alloc((size_t)N * 4);
    int*   rs     = (int*)alloc((size_t)(N + 1) * 4);
    int*   gcur   = (int*)alloc(256 * 4);
    int*   bsum   = (int*)alloc(256 * 4);
    int*   boff   = (int*)alloc(256 * 4);
    u16*   wembt  = (u16*)alloc((size_t)128 * 128 * 2);
    u16*   wfct   = (u16*)alloc((size_t)L * 128 * 384 * 2);
    float* bnAll  = (float*)alloc((size_t)L * 256 * 4);
    float* hg     = (float*)alloc((size_t)G * 128 * 4);
    float* cnts   = (float*)alloc((size_t)G * 4);

    hipMemsetAsync(cnt, 0, (size_t)N * 4, stream);
    hipMemsetAsync(gcur, 0, 256 * 4, stream);
    hipMemsetAsync(hg, 0, (size_t)G * 128 * 4, stream);
    hipMemsetAsync(cnts, 0, (size_t)G * 4, stream);
    hipMemsetAsync(bnAll, 0, (size_t)L * 256 * 4, stream);
    hipMemsetAsync(psrc + E, 0, 16 * 4, stream);   // zero pad (safe gather idx)

    // weight prep
    prep_embW<<<(128 * 128 + 255) / 256, 256, 0, stream>>>(emb_W, wembt);
    prep_fcW<<<(L * 128 * 384 + 255) / 256, 256, 0, stream>>>(fc_W, wfct, L * 128 * 384);

    // CSR build: hist -> scan -> graph-bucket passes (bucketB also fills pdst)
    const int nb = (N + 255) / 256;
    hist_kernel<<<(E + 255) / 256, 256, 0, stream>>>(dst, cnt, E);
    scan_partial<<<nb, 256, 0, stream>>>(cnt, bsum, N);
    scan_bsums<<<1, 256, 0, stream>>>(bsum, boff, nb);
    scan_final<<<nb, 256, 0, stream>>>(cnt, boff, rs, N);
    bucketA<<<(E + 4095) / 4096, 256, 0, stream>>>(src, dst, rs, gcur, tmp, E, npg, G);
    bucketB<<<G, 1024, 0, stream>>>(tmp, rs, psrc, pdst, npg);
    gw_kernel<<<(E + 255) / 256, 256, 0, stream>>>(psrc, pdst, cnt, ppW, ppb, mu, isig,
                                                   pgw, E, Epad, L);

    // node embedding (fp32 x converted in staging)
    const int gblocks = (N + 127) / 128;
    gemm_mfma<<<gblocks, 256, 0, stream>>>(x, wembt, N, 128, emb_b, nullptr, hb, 0, nullptr);

    const float invN = 1.0f / (float)N;
    for (int l = 0; l < L; l++) {
        agg_kernel<<<(N + 3) / 4, 256, 0, stream>>>(hb, pgw + (size_t)l * Epad * 4, psrc, rs,
                                                    t, sk, N);
        gemm_mfma<<<gblocks, 256, 0, stream>>>(t, wfct + (size_t)l * 128 * 384, N, 384,
                                               fc_b + (size_t)l * 384, sk, aggB, 1,
                                               bnAll + (size_t)l * 256);
        bn_apply<<<(N * 32 + 255) / 256, 256, 0, stream>>>(hb, aggB, bnAll + (size_t)l * 256,
                                                           gamma + l * 128, beta + l * 128, invN, N);
    }

    readout_kernel<<<(N + 24) / 25, 128, 0, stream>>>(hb, gids, hg, cnts, N);
    mlp_kernel<<<G, 128, 0, stream>>>(hg, cnts, W1, b1, W2, b2, W3, b3, out);
}